// Round 3
// baseline (315.579 us; speedup 1.0000x reference)
//
#include <hip/hip_runtime.h>
#include <hip/hip_cooperative_groups.h>
#include <math.h>

#define NTH 256

namespace cg = cooperative_groups;

typedef float v4f __attribute__((ext_vector_type(4)));

// ============ workspace float offsets ============
// ONLY final tables now (read wave-uniform by the actor phase): 1940 floats.
// WQ0 / M / TB are pre-scaled by 1/sqrt(32).
enum : int {
  WQ0_OFF = 0,        // [4][19][8]  = 608
  M_OFF   = 608,      // [36][32]    = 1152
  TB_OFF  = 1760,     // [4][8]      = 32
  AO1_OFF = 1792,     // [36][4]     = 144
  B1H_OFF = 1936      // [4]         = 4
};

// ---------------- obs tile -> LDS (coalesced v4f) ----------------
__device__ __forceinline__ void stage_obs(const float* __restrict__ obs,
    v4f* sObsV, float* sObs, int tile, int n, int tid)
{
  const size_t total_f = (size_t)n * 37;
  const size_t v4base = (size_t)tile * (NTH * 37 / 4);
  const v4f* src = (const v4f*)obs;
#pragma unroll
  for (int k = 0; k < 9; k++) {
    const size_t vi = v4base + k * NTH + tid;
    if (vi * 4 + 4 <= total_f) {
      sObsV[k * NTH + tid] = src[vi];
    } else {
      for (int e = 0; e < 4; e++) {
        const size_t f = vi * 4 + e;
        if (f < total_f) sObs[(k * NTH + tid) * 4 + e] = obs[f];
      }
    }
  }
  if (tid < 64) {
    const size_t vi = v4base + 9 * NTH + tid;
    if (vi * 4 + 4 <= total_f) {
      sObsV[9 * NTH + tid] = src[vi];
    } else {
      for (int e = 0; e < 4; e++) {
        const size_t f = vi * 4 + e;
        if (f < total_f) sObs[(9 * NTH + tid) * 4 + e] = obs[f];
      }
    }
  }
}

// ---------------- self-contained prep for one block ----------------
// Blocks 0..35: M row t   (P -> AO0 -> G -> M; split-K + LDS reduce per phase)
// Blocks 36..71: AO1 row  (P1 -> R -> AO1)
// Block 72: TB            (B0 -> Gb -> TB)
// Blocks 73..75: WQ0      (608 direct v4f dots)
// Block 76: B1H           (BB1 -> B1H)
__device__ __forceinline__ void prep_block(
    int b, int tid,
    const float* __restrict__ wq0,  const float* __restrict__ wak0, const float* __restrict__ wok0,
    const float* __restrict__ wav0, const float* __restrict__ wov0,
    const float* __restrict__ apw0, const float* __restrict__ opw0,
    const float* __restrict__ fpw0, const float* __restrict__ fpb0,
    const float* __restrict__ apb0, const float* __restrict__ opb0,
    const float* __restrict__ wq1,  const float* __restrict__ wak1, const float* __restrict__ wok1,
    const float* __restrict__ wav1, const float* __restrict__ wov1,
    const float* __restrict__ apw1, const float* __restrict__ opw1,
    const float* __restrict__ fpw1, const float* __restrict__ fpb1,
    const float* __restrict__ apb1, const float* __restrict__ opb1,
    const float* __restrict__ headw, const float* __restrict__ headb,
    float* __restrict__ ws,
    v4f* sred, float* sVecA, float* sVecB, float* sVecC)
{
  const float scale = 0.17677669529663687f;   // 1/sqrt(32)
  const int x4 = tid & 31, g = tid >> 5;      // 8 K-groups x 32 v4f columns

  if (b < 72) {
    const int isL1 = (b >= 36) ? 1 : 0;
    const int t = isL1 ? b - 36 : b;
    const int h = t / 9, i = t % 9;
    // ---- phase 1: P[128] = w . PW columns (split-K 8x, 16 v4f loads/thread)
    {
      const float* w = (i < 7 ? (isL1 ? wav1 : wav0) + i * 512
                              : (isL1 ? wov1 : wov0) + (i - 7) * 512) + h * 128;
      const v4f* P4 = (const v4f*)((i < 7 ? (isL1 ? apw1 : apw0)
                                          : (isL1 ? opw1 : opw0)) + h * 16384);
      v4f acc = (v4f)0.f;
#pragma unroll
      for (int c = g * 16; c < g * 16 + 16; ++c) acc += w[c] * P4[c * 32 + x4];
      sred[tid] = acc;
    }
    __syncthreads();
    if (g == 0) {
      v4f r = sred[x4];
#pragma unroll
      for (int q = 1; q < 8; ++q) r += sred[q * 32 + x4];
      ((v4f*)sVecA)[x4] = r;
    }
    __syncthreads();
    // ---- phase 2: AO[128] = P . fpw-half columns
    {
      const v4f* F4 = (const v4f*)((isL1 ? fpw1 : fpw0) + (i < 7 ? 0 : 16384));
      v4f acc = (v4f)0.f;
#pragma unroll
      for (int u = g * 16; u < g * 16 + 16; ++u) acc += sVecA[u] * F4[u * 32 + x4];
      sred[tid] = acc;
    }
    __syncthreads();
    if (g == 0) {
      v4f r = sred[x4];
#pragma unroll
      for (int q = 1; q < 8; ++q) r += sred[q * 32 + x4];
      ((v4f*)sVecC)[x4] = r;
    }
    __syncthreads();
    if (!isL1) {
      // ---- phase 3: G[512] = AO0 . wq1   (2 K-groups x 128 v4f columns)
      {
        const int hd4 = tid & 127, g2 = tid >> 7;
        const v4f* W4 = (const v4f*)wq1;
        v4f acc = (v4f)0.f;
#pragma unroll 32
        for (int c = g2 * 64; c < g2 * 64 + 64; ++c) acc += sVecC[c] * W4[c * 128 + hd4];
        sred[tid] = acc;
      }
      __syncthreads();
      if (tid < 128) ((v4f*)sVecB)[tid] = sred[tid] + sred[tid + 128];
      __syncthreads();
      // ---- phase 4: M[t][h2*8+j2] = scale * <G[h2*128..], wb1 row>
      if (tid < 32) {
        const int h2 = tid >> 3, j2 = tid & 7;
        const v4f* wb = (const v4f*)(((j2 < 6) ? wak1 + j2 * 512 : wok1 + (j2 - 6) * 512) + h2 * 128);
        const v4f* Gv = (const v4f*)(sVecB + h2 * 128);
        v4f a = (v4f)0.f;
#pragma unroll
        for (int c4 = 0; c4 < 32; ++c4) a += Gv[c4] * wb[c4];
        ws[M_OFF + t * 32 + tid] = (a[0] + a[1] + a[2] + a[3]) * scale;
      }
    } else {
      // ---- phase 3: AO1 row = sum_j R[j] * headw[j][0..3]
      if (tid < 128) sred[tid] = sVecC[tid] * ((const v4f*)headw)[tid];
      __syncthreads();
      if (tid < 32) sred[tid] = sred[tid] + sred[tid + 32] + sred[tid + 64] + sred[tid + 96];
      __syncthreads();
      if (tid == 0) {
        v4f a = (v4f)0.f;
#pragma unroll
        for (int q = 0; q < 32; ++q) a += sred[q];
        ((v4f*)(ws + AO1_OFF))[t] = a;
      }
    }
  } else if (b == 72) {
    // ---- TB: B0[128] -> Gb[512] -> TB[32]
    {
      const v4f* F4 = (const v4f*)fpw0;
      v4f acc = (v4f)0.f;
#pragma unroll 16
      for (int r = g * 32; r < g * 32 + 32; ++r) {
        const float cf = (r < 128) ? apb0[r] : opb0[r - 128];
        acc += cf * F4[r * 32 + x4];
      }
      sred[tid] = acc;
    }
    __syncthreads();
    if (g == 0) {
      v4f r = sred[x4];
#pragma unroll
      for (int q = 1; q < 8; ++q) r += sred[q * 32 + x4];
      ((v4f*)sVecA)[x4] = r + ((const v4f*)fpb0)[x4];
    }
    __syncthreads();
    {
      const int hd4 = tid & 127, g2 = tid >> 7;
      const v4f* W4 = (const v4f*)wq1;
      v4f acc = (v4f)0.f;
#pragma unroll 32
      for (int c = g2 * 64; c < g2 * 64 + 64; ++c) acc += sVecA[c] * W4[c * 128 + hd4];
      sred[tid] = acc;
    }
    __syncthreads();
    if (tid < 128) ((v4f*)sVecB)[tid] = sred[tid] + sred[tid + 128];
    __syncthreads();
    if (tid < 32) {
      const int h2 = tid >> 3, j2 = tid & 7;
      const v4f* wb = (const v4f*)(((j2 < 6) ? wak1 + j2 * 512 : wok1 + (j2 - 6) * 512) + h2 * 128);
      const v4f* Gv = (const v4f*)(sVecB + h2 * 128);
      v4f a = (v4f)0.f;
#pragma unroll
      for (int c4 = 0; c4 < 32; ++c4) a += Gv[c4] * wb[c4];
      ws[TB_OFF + tid] = (a[0] + a[1] + a[2] + a[3]) * scale;
    }
  } else if (b < 76) {
    // ---- WQ0[h][r][j] (608 entries, pre-scaled)
    const int idx = (b - 73) * NTH + tid;
    if (idx < 608) {
      const int j = idx & 7, r = (idx >> 3) % 19, h = idx / 152;
      const v4f* a4 = (const v4f*)(wq0 + r * 512 + h * 128);
      const v4f* b4 = (const v4f*)(((j < 6) ? wak0 + j * 512 : wok0 + (j - 6) * 512) + h * 128);
      v4f s = (v4f)0.f;
#pragma unroll 16
      for (int c4 = 0; c4 < 32; ++c4) s += a4[c4] * b4[c4];
      ws[WQ0_OFF + idx] = (s[0] + s[1] + s[2] + s[3]) * scale;
    }
  } else {
    // ---- B1H: BB1[128] -> B1H[4]
    {
      const v4f* F4 = (const v4f*)fpw1;
      v4f acc = (v4f)0.f;
#pragma unroll 16
      for (int r = g * 32; r < g * 32 + 32; ++r) {
        const float cf = (r < 128) ? apb1[r] : opb1[r - 128];
        acc += cf * F4[r * 32 + x4];
      }
      sred[tid] = acc;
    }
    __syncthreads();
    if (g == 0) {
      v4f r = sred[x4];
#pragma unroll
      for (int q = 1; q < 8; ++q) r += sred[q * 32 + x4];
      ((v4f*)sVecA)[x4] = r + ((const v4f*)fpb1)[x4];
    }
    __syncthreads();
    if (tid < 128) sred[tid] = sVecA[tid] * ((const v4f*)headw)[tid];
    __syncthreads();
    if (tid < 32) sred[tid] = sred[tid] + sred[tid + 32] + sred[tid + 64] + sred[tid + 96];
    __syncthreads();
    if (tid == 0) {
      v4f a = *(const v4f*)headb;
#pragma unroll
      for (int q = 0; q < 32; ++q) a += sred[q];
      ((v4f*)(ws + B1H_OFF))[0] = a;
    }
  }
}

// ---------------- actor compute for one sample (obs row in sObs[tid*37..]) ----------------
__device__ __forceinline__ void actor_compute(
    const float* sObs, int tid, int gid,
    const float* __restrict__ ws,
    float ca0, float co0, float ca1, float co1,
    float* __restrict__ out)
{
  const v4f* __restrict__ tbl = (const v4f*)ws;

  float o[37];
#pragma unroll
  for (int i = 0; i < 37; i++) o[i] = sObs[tid * 37 + i];

  float qf[19];
#pragma unroll
  for (int i = 0; i < 12; i++) qf[i] = o[i];
#pragma unroll
  for (int i = 0; i < 7; i++) qf[12 + i] = o[30 + i];
  float nb[2][6];
#pragma unroll
  for (int k2 = 0; k2 < 2; k2++)
#pragma unroll
    for (int i = 0; i < 6; i++) nb[k2][i] = o[12 + 6 * k2 + i];
  const float nbv6[2] = { o[24], o[25] };
  const float obf[2][2] = { { o[26], o[27] }, { o[28], o[29] } };
  const float ax = o[0], ay = o[1];

  float dista[2], disto[2];
#pragma unroll
  for (int k2 = 0; k2 < 2; k2++) {
    float dx = ax - nb[k2][0], dy = ay - nb[k2][1];
    dista[k2] = sqrtf(dx * dx + dy * dy);
    float ex = ax - obf[k2][0], ey = ay - obf[k2][1];
    disto[k2] = sqrtf(ex * ex + ey * ey);
  }
  float dwa0[2], dwo0[2], dwa1[2], dwo1[2];
#pragma unroll
  for (int k2 = 0; k2 < 2; k2++) {
    dwa0[k2] = __expf(-ca0 * dista[k2]);
    dwo0[k2] = __expf(-co0 * disto[k2]);
    dwa1[k2] = __expf(-ca1 * dista[k2]);
    dwo1[k2] = __expf(-co1 * disto[k2]);
  }

  // layer 0 query fold (pre-scaled tables)
  v4f t0v[8];
#pragma unroll
  for (int z = 0; z < 8; z++) t0v[z] = (v4f)0.f;
#pragma unroll
  for (int h = 0; h < 4; h++) {
#pragma unroll
    for (int r = 0; r < 19; r++) {
      float q = qf[r];
      t0v[h * 2 + 0] += tbl[(h * 19 + r) * 2 + 0] * q;
      t0v[h * 2 + 1] += tbl[(h * 19 + r) * 2 + 1] * q;
    }
  }

  float wff[36];
#pragma unroll
  for (int h = 0; h < 4; h++) {
    float la[2], lo[2];
#pragma unroll
    for (int k2 = 0; k2 < 2; k2++) {
      float da = t0v[h*2][0]*nb[k2][0] + t0v[h*2][1]*nb[k2][1] + t0v[h*2][2]*nb[k2][2]
               + t0v[h*2][3]*nb[k2][3] + t0v[h*2+1][0]*nb[k2][4] + t0v[h*2+1][1]*nb[k2][5];
      la[k2] = da * dwa0[k2];
      float dof = t0v[h*2+1][2]*obf[k2][0] + t0v[h*2+1][3]*obf[k2][1];
      lo[k2] = dof * dwo0[k2];
    }
    float e  = __expf(la[1] - la[0]); float aa1 = e  / (1.f + e);  float aa0 = 1.f - aa1;
    float eo = __expf(lo[1] - lo[0]); float bo1 = eo / (1.f + eo); float bo0 = 1.f - bo1;
#pragma unroll
    for (int i = 0; i < 6; i++) wff[h * 9 + i] = aa0 * nb[0][i] + aa1 * nb[1][i];
    wff[h * 9 + 6] = aa0 * nbv6[0] + aa1 * nbv6[1];
    wff[h * 9 + 7] = bo0 * obf[0][0] + bo1 * obf[1][0];
    wff[h * 9 + 8] = bo0 * obf[0][1] + bo1 * obf[1][1];
  }

  // layer 1 query fold via M
  v4f t1v[8];
#pragma unroll
  for (int q = 0; q < 8; q++) t1v[q] = tbl[440 + q];
#pragma unroll
  for (int t = 0; t < 36; t++) {
    float f = wff[t];
#pragma unroll
    for (int q = 0; q < 8; q++)
      t1v[q] += tbl[152 + t * 8 + q] * f;
  }

  float wf1f[36];
#pragma unroll
  for (int h = 0; h < 4; h++) {
    float la[2], lo[2];
#pragma unroll
    for (int k2 = 0; k2 < 2; k2++) {
      float da = t1v[h*2][0]*nb[k2][0] + t1v[h*2][1]*nb[k2][1] + t1v[h*2][2]*nb[k2][2]
               + t1v[h*2][3]*nb[k2][3] + t1v[h*2+1][0]*nb[k2][4] + t1v[h*2+1][1]*nb[k2][5];
      la[k2] = da * dwa1[k2];
      float dof = t1v[h*2+1][2]*obf[k2][0] + t1v[h*2+1][3]*obf[k2][1];
      lo[k2] = dof * dwo1[k2];
    }
    float e  = __expf(la[1] - la[0]); float aa1 = e  / (1.f + e);  float aa0 = 1.f - aa1;
    float eo = __expf(lo[1] - lo[0]); float bo1 = eo / (1.f + eo); float bo0 = 1.f - bo1;
#pragma unroll
    for (int i = 0; i < 6; i++) wf1f[h * 9 + i] = aa0 * nb[0][i] + aa1 * nb[1][i];
    wf1f[h * 9 + 6] = aa0 * nbv6[0] + aa1 * nbv6[1];
    wf1f[h * 9 + 7] = bo0 * obf[0][0] + bo1 * obf[1][0];
    wf1f[h * 9 + 8] = bo0 * obf[0][1] + bo1 * obf[1][1];
  }

  v4f acc = tbl[484];
#pragma unroll
  for (int t = 0; t < 36; t++)
    acc += tbl[448 + t] * wf1f[t];
  ((v4f*)out)[gid] = acc;
}

// ---------------- the fused cooperative kernel ----------------
__global__ __launch_bounds__(NTH, 2) void fused_all(
    const float* __restrict__ obs,
    const float* __restrict__ wq0,  const float* __restrict__ wak0, const float* __restrict__ wok0,
    const float* __restrict__ wav0, const float* __restrict__ wov0,
    const float* __restrict__ apw0, const float* __restrict__ opw0,
    const float* __restrict__ fpw0, const float* __restrict__ fpb0,
    const float* __restrict__ apb0, const float* __restrict__ opb0,
    const float* __restrict__ wq1,  const float* __restrict__ wak1, const float* __restrict__ wok1,
    const float* __restrict__ wav1, const float* __restrict__ wov1,
    const float* __restrict__ apw1, const float* __restrict__ opw1,
    const float* __restrict__ fpw1, const float* __restrict__ fpb1,
    const float* __restrict__ apb1, const float* __restrict__ opb1,
    const float* __restrict__ headw, const float* __restrict__ headb,
    const float* __restrict__ pca0, const float* __restrict__ pco0,
    const float* __restrict__ pca1, const float* __restrict__ pco1,
    float* __restrict__ out, float* __restrict__ ws, int n)
{
  const int tid = threadIdx.x;
  const int b = blockIdx.x;

  __shared__ v4f sObsV[NTH * 37 / 4];   // 37888 B
  __shared__ v4f sred[NTH];             // 4096 B
  __shared__ float sVecA[128];
  __shared__ float sVecB[512];
  __shared__ float sVecC[128];
  float* sObs = (float*)sObsV;

  // phase A: stage own obs tile (overlaps prep latency), then prep work
  if ((long long)b * NTH < n) stage_obs(obs, sObsV, sObs, b, n, tid);
  if (b < 77)
    prep_block(b, tid, wq0, wak0, wok0, wav0, wov0, apw0, opw0, fpw0, fpb0,
               apb0, opb0, wq1, wak1, wok1, wav1, wov1, apw1, opw1, fpw1,
               fpb1, apb1, opb1, headw, headb, ws, sred, sVecA, sVecB, sVecC);

  __threadfence();
  cg::this_grid().sync();

  // phase B: actor (grid-stride; first tile already staged)
  const float ca0 = pca0[0], co0 = pco0[0], ca1 = pca1[0], co1 = pco1[0];
  int tile = b;
  bool first = true;
  while ((long long)tile * NTH < n) {
    if (!first) {
      __syncthreads();
      stage_obs(obs, sObsV, sObs, tile, n, tid);
      __syncthreads();
    }
    const int gid = tile * NTH + tid;
    if (gid < n) actor_compute(sObs, tid, gid, ws, ca0, co0, ca1, co1, out);
    tile += gridDim.x;
    first = false;
  }
}

// ---------------- fallback (non-cooperative) path ----------------
__global__ __launch_bounds__(NTH) void prep_one(
    const float* __restrict__ wq0,  const float* __restrict__ wak0, const float* __restrict__ wok0,
    const float* __restrict__ wav0, const float* __restrict__ wov0,
    const float* __restrict__ apw0, const float* __restrict__ opw0,
    const float* __restrict__ fpw0, const float* __restrict__ fpb0,
    const float* __restrict__ apb0, const float* __restrict__ opb0,
    const float* __restrict__ wq1,  const float* __restrict__ wak1, const float* __restrict__ wok1,
    const float* __restrict__ wav1, const float* __restrict__ wov1,
    const float* __restrict__ apw1, const float* __restrict__ opw1,
    const float* __restrict__ fpw1, const float* __restrict__ fpb1,
    const float* __restrict__ apb1, const float* __restrict__ opb1,
    const float* __restrict__ headw, const float* __restrict__ headb,
    float* __restrict__ ws)
{
  __shared__ v4f sred[NTH];
  __shared__ float sVecA[128];
  __shared__ float sVecB[512];
  __shared__ float sVecC[128];
  prep_block(blockIdx.x, threadIdx.x, wq0, wak0, wok0, wav0, wov0, apw0, opw0,
             fpw0, fpb0, apb0, opb0, wq1, wak1, wok1, wav1, wov1, apw1, opw1,
             fpw1, fpb1, apb1, opb1, headw, headb, ws, sred, sVecA, sVecB, sVecC);
}

__global__ __launch_bounds__(NTH) void actor_k(
    const float* __restrict__ obs, const float* __restrict__ ws,
    const float* __restrict__ pca0, const float* __restrict__ pco0,
    const float* __restrict__ pca1, const float* __restrict__ pco1,
    float* __restrict__ out, int n)
{
  const int tid = threadIdx.x;
  const int gid = blockIdx.x * NTH + tid;
  __shared__ v4f sObsV[NTH * 37 / 4];
  float* sObs = (float*)sObsV;
  stage_obs(obs, sObsV, sObs, blockIdx.x, n, tid);
  __syncthreads();
  if (gid >= n) return;
  actor_compute(sObs, tid, gid, ws, pca0[0], pco0[0], pca1[0], pco1[0], out);
}

extern "C" void kernel_launch(void* const* d_in, const int* in_sizes, int n_in,
                              void* d_out, int out_size, void* d_ws, size_t ws_size,
                              hipStream_t stream)
{
  const float* obs  = (const float*)d_in[0];
  const float* wq0  = (const float*)d_in[1];
  const float* wak0 = (const float*)d_in[2];
  const float* wav0 = (const float*)d_in[3];
  const float* wok0 = (const float*)d_in[4];
  const float* wov0 = (const float*)d_in[5];
  const float* apw0 = (const float*)d_in[6];
  const float* apb0 = (const float*)d_in[7];
  const float* opw0 = (const float*)d_in[8];
  const float* opb0 = (const float*)d_in[9];
  const float* fpw0 = (const float*)d_in[10];
  const float* fpb0 = (const float*)d_in[11];
  const float* ca0  = (const float*)d_in[12];
  const float* co0  = (const float*)d_in[13];
  const float* wq1  = (const float*)d_in[14];
  const float* wak1 = (const float*)d_in[15];
  const float* wav1 = (const float*)d_in[16];
  const float* wok1 = (const float*)d_in[17];
  const float* wov1 = (const float*)d_in[18];
  const float* apw1 = (const float*)d_in[19];
  const float* apb1 = (const float*)d_in[20];
  const float* opw1 = (const float*)d_in[21];
  const float* opb1 = (const float*)d_in[22];
  const float* fpw1 = (const float*)d_in[23];
  const float* fpb1 = (const float*)d_in[24];
  const float* ca1  = (const float*)d_in[25];
  const float* co1  = (const float*)d_in[26];
  const float* headw = (const float*)d_in[27];
  const float* headb = (const float*)d_in[28];
  float* ws = (float*)d_ws;
  float* outp = (float*)d_out;
  int n = in_sizes[0] / 37;

  const int nblk = (n + NTH - 1) / NTH;
  int NB = nblk < 77 ? 77 : nblk;
  if (NB > 512) NB = 512;   // cooperative capacity: 2 blocks/CU x 256 CUs

  void* args[] = {
    (void*)&obs,
    (void*)&wq0, (void*)&wak0, (void*)&wok0,
    (void*)&wav0, (void*)&wov0, (void*)&apw0, (void*)&opw0,
    (void*)&fpw0, (void*)&fpb0, (void*)&apb0, (void*)&opb0,
    (void*)&wq1, (void*)&wak1, (void*)&wok1,
    (void*)&wav1, (void*)&wov1, (void*)&apw1, (void*)&opw1,
    (void*)&fpw1, (void*)&fpb1, (void*)&apb1, (void*)&opb1,
    (void*)&headw, (void*)&headb,
    (void*)&ca0, (void*)&co0, (void*)&ca1, (void*)&co1,
    (void*)&outp, (void*)&ws, (void*)&n
  };

  hipError_t rc = hipLaunchCooperativeKernel(
      reinterpret_cast<void*>(fused_all), dim3(NB), dim3(NTH), args, 0, stream);
  if (rc != hipSuccess) {
    (void)hipGetLastError();   // clear sticky error, fall back to 2-kernel path
    prep_one<<<77, NTH, 0, stream>>>(
        wq0, wak0, wok0, wav0, wov0, apw0, opw0, fpw0, fpb0, apb0, opb0,
        wq1, wak1, wok1, wav1, wov1, apw1, opw1, fpw1, fpb1, apb1, opb1,
        headw, headb, ws);
    actor_k<<<nblk, NTH, 0, stream>>>(obs, ws, ca0, co0, ca1, co1, outp, n);
  }
}

// Round 4
// 142.500 us; speedup vs baseline: 2.2146x; 2.2146x over previous
//
#include <hip/hip_runtime.h>
#include <math.h>

#define NTH 256

typedef float v4f __attribute__((ext_vector_type(4)));

// ============ workspace float offsets ============
// ONLY final tables (read wave-uniform by the actor): 1940 floats.
// WQ0 / M / TB are pre-scaled by 1/sqrt(32).
enum : int {
  WQ0_OFF = 0,        // [4][19][8]  = 608
  M_OFF   = 608,      // [36][32]    = 1152
  TB_OFF  = 1760,     // [4][8]      = 32
  AO1_OFF = 1792,     // [36][4]     = 144
  B1H_OFF = 1936      // [4]         = 4
};

// ---------------- obs tile -> LDS (coalesced v4f) ----------------
__device__ __forceinline__ void stage_obs(const float* __restrict__ obs,
    v4f* sObsV, float* sObs, int tile, int n, int tid)
{
  const size_t total_f = (size_t)n * 37;
  const size_t v4base = (size_t)tile * (NTH * 37 / 4);
  const v4f* src = (const v4f*)obs;
#pragma unroll
  for (int k = 0; k < 9; k++) {
    const size_t vi = v4base + k * NTH + tid;
    if (vi * 4 + 4 <= total_f) {
      sObsV[k * NTH + tid] = src[vi];
    } else {
      for (int e = 0; e < 4; e++) {
        const size_t f = vi * 4 + e;
        if (f < total_f) sObs[(k * NTH + tid) * 4 + e] = obs[f];
      }
    }
  }
  if (tid < 64) {
    const size_t vi = v4base + 9 * NTH + tid;
    if (vi * 4 + 4 <= total_f) {
      sObsV[9 * NTH + tid] = src[vi];
    } else {
      for (int e = 0; e < 4; e++) {
        const size_t f = vi * 4 + e;
        if (f < total_f) sObs[(9 * NTH + tid) * 4 + e] = obs[f];
      }
    }
  }
}

// ---------------- self-contained prep for one block (verified in R3) ----------------
// Blocks 0..35: M row t   (P -> AO0 -> G -> M; split-K + LDS reduce per phase)
// Blocks 36..71: AO1 row  (P1 -> R -> AO1)
// Block 72: TB            (B0 -> Gb -> TB)
// Blocks 73..75: WQ0      (608 direct v4f dots)
// Block 76: B1H           (BB1 -> B1H)
__device__ __forceinline__ void prep_block(
    int b, int tid,
    const float* __restrict__ wq0,  const float* __restrict__ wak0, const float* __restrict__ wok0,
    const float* __restrict__ wav0, const float* __restrict__ wov0,
    const float* __restrict__ apw0, const float* __restrict__ opw0,
    const float* __restrict__ fpw0, const float* __restrict__ fpb0,
    const float* __restrict__ apb0, const float* __restrict__ opb0,
    const float* __restrict__ wq1,  const float* __restrict__ wak1, const float* __restrict__ wok1,
    const float* __restrict__ wav1, const float* __restrict__ wov1,
    const float* __restrict__ apw1, const float* __restrict__ opw1,
    const float* __restrict__ fpw1, const float* __restrict__ fpb1,
    const float* __restrict__ apb1, const float* __restrict__ opb1,
    const float* __restrict__ headw, const float* __restrict__ headb,
    float* __restrict__ ws,
    v4f* sred, float* sVecA, float* sVecB, float* sVecC)
{
  const float scale = 0.17677669529663687f;   // 1/sqrt(32)
  const int x4 = tid & 31, g = tid >> 5;      // 8 K-groups x 32 v4f columns

  if (b < 72) {
    const int isL1 = (b >= 36) ? 1 : 0;
    const int t = isL1 ? b - 36 : b;
    const int h = t / 9, i = t % 9;
    // ---- phase 1: P[128] = w . PW columns (split-K 8x, 16 v4f loads/thread)
    {
      const float* w = (i < 7 ? (isL1 ? wav1 : wav0) + i * 512
                              : (isL1 ? wov1 : wov0) + (i - 7) * 512) + h * 128;
      const v4f* P4 = (const v4f*)((i < 7 ? (isL1 ? apw1 : apw0)
                                          : (isL1 ? opw1 : opw0)) + h * 16384);
      v4f acc = (v4f)0.f;
#pragma unroll
      for (int c = g * 16; c < g * 16 + 16; ++c) acc += w[c] * P4[c * 32 + x4];
      sred[tid] = acc;
    }
    __syncthreads();
    if (g == 0) {
      v4f r = sred[x4];
#pragma unroll
      for (int q = 1; q < 8; ++q) r += sred[q * 32 + x4];
      ((v4f*)sVecA)[x4] = r;
    }
    __syncthreads();
    // ---- phase 2: AO[128] = P . fpw-half columns
    {
      const v4f* F4 = (const v4f*)((isL1 ? fpw1 : fpw0) + (i < 7 ? 0 : 16384));
      v4f acc = (v4f)0.f;
#pragma unroll
      for (int u = g * 16; u < g * 16 + 16; ++u) acc += sVecA[u] * F4[u * 32 + x4];
      sred[tid] = acc;
    }
    __syncthreads();
    if (g == 0) {
      v4f r = sred[x4];
#pragma unroll
      for (int q = 1; q < 8; ++q) r += sred[q * 32 + x4];
      ((v4f*)sVecC)[x4] = r;
    }
    __syncthreads();
    if (!isL1) {
      // ---- phase 3: G[512] = AO0 . wq1   (2 K-groups x 128 v4f columns)
      {
        const int hd4 = tid & 127, g2 = tid >> 7;
        const v4f* W4 = (const v4f*)wq1;
        v4f acc = (v4f)0.f;
#pragma unroll 32
        for (int c = g2 * 64; c < g2 * 64 + 64; ++c) acc += sVecC[c] * W4[c * 128 + hd4];
        sred[tid] = acc;
      }
      __syncthreads();
      if (tid < 128) ((v4f*)sVecB)[tid] = sred[tid] + sred[tid + 128];
      __syncthreads();
      // ---- phase 4: M[t][h2*8+j2] = scale * <G[h2*128..], wb1 row>
      if (tid < 32) {
        const int h2 = tid >> 3, j2 = tid & 7;
        const v4f* wb = (const v4f*)(((j2 < 6) ? wak1 + j2 * 512 : wok1 + (j2 - 6) * 512) + h2 * 128);
        const v4f* Gv = (const v4f*)(sVecB + h2 * 128);
        v4f a = (v4f)0.f;
#pragma unroll
        for (int c4 = 0; c4 < 32; ++c4) a += Gv[c4] * wb[c4];
        ws[M_OFF + t * 32 + tid] = (a[0] + a[1] + a[2] + a[3]) * scale;
      }
    } else {
      // ---- phase 3: AO1 row = sum_j R[j] * headw[j][0..3]
      if (tid < 128) sred[tid] = sVecC[tid] * ((const v4f*)headw)[tid];
      __syncthreads();
      if (tid < 32) sred[tid] = sred[tid] + sred[tid + 32] + sred[tid + 64] + sred[tid + 96];
      __syncthreads();
      if (tid == 0) {
        v4f a = (v4f)0.f;
#pragma unroll
        for (int q = 0; q < 32; ++q) a += sred[q];
        ((v4f*)(ws + AO1_OFF))[t] = a;
      }
    }
  } else if (b == 72) {
    // ---- TB: B0[128] -> Gb[512] -> TB[32]
    {
      const v4f* F4 = (const v4f*)fpw0;
      v4f acc = (v4f)0.f;
#pragma unroll 16
      for (int r = g * 32; r < g * 32 + 32; ++r) {
        const float cf = (r < 128) ? apb0[r] : opb0[r - 128];
        acc += cf * F4[r * 32 + x4];
      }
      sred[tid] = acc;
    }
    __syncthreads();
    if (g == 0) {
      v4f r = sred[x4];
#pragma unroll
      for (int q = 1; q < 8; ++q) r += sred[q * 32 + x4];
      ((v4f*)sVecA)[x4] = r + ((const v4f*)fpb0)[x4];
    }
    __syncthreads();
    {
      const int hd4 = tid & 127, g2 = tid >> 7;
      const v4f* W4 = (const v4f*)wq1;
      v4f acc = (v4f)0.f;
#pragma unroll 32
      for (int c = g2 * 64; c < g2 * 64 + 64; ++c) acc += sVecA[c] * W4[c * 128 + hd4];
      sred[tid] = acc;
    }
    __syncthreads();
    if (tid < 128) ((v4f*)sVecB)[tid] = sred[tid] + sred[tid + 128];
    __syncthreads();
    if (tid < 32) {
      const int h2 = tid >> 3, j2 = tid & 7;
      const v4f* wb = (const v4f*)(((j2 < 6) ? wak1 + j2 * 512 : wok1 + (j2 - 6) * 512) + h2 * 128);
      const v4f* Gv = (const v4f*)(sVecB + h2 * 128);
      v4f a = (v4f)0.f;
#pragma unroll
      for (int c4 = 0; c4 < 32; ++c4) a += Gv[c4] * wb[c4];
      ws[TB_OFF + tid] = (a[0] + a[1] + a[2] + a[3]) * scale;
    }
  } else if (b < 76) {
    // ---- WQ0[h][r][j] (608 entries, pre-scaled)
    const int idx = (b - 73) * NTH + tid;
    if (idx < 608) {
      const int j = idx & 7, r = (idx >> 3) % 19, h = idx / 152;
      const v4f* a4 = (const v4f*)(wq0 + r * 512 + h * 128);
      const v4f* b4 = (const v4f*)(((j < 6) ? wak0 + j * 512 : wok0 + (j - 6) * 512) + h * 128);
      v4f s = (v4f)0.f;
#pragma unroll 16
      for (int c4 = 0; c4 < 32; ++c4) s += a4[c4] * b4[c4];
      ws[WQ0_OFF + idx] = (s[0] + s[1] + s[2] + s[3]) * scale;
    }
  } else {
    // ---- B1H: BB1[128] -> B1H[4]
    {
      const v4f* F4 = (const v4f*)fpw1;
      v4f acc = (v4f)0.f;
#pragma unroll 16
      for (int r = g * 32; r < g * 32 + 32; ++r) {
        const float cf = (r < 128) ? apb1[r] : opb1[r - 128];
        acc += cf * F4[r * 32 + x4];
      }
      sred[tid] = acc;
    }
    __syncthreads();
    if (g == 0) {
      v4f r = sred[x4];
#pragma unroll
      for (int q = 1; q < 8; ++q) r += sred[q * 32 + x4];
      ((v4f*)sVecA)[x4] = r + ((const v4f*)fpb1)[x4];
    }
    __syncthreads();
    if (tid < 128) sred[tid] = sVecA[tid] * ((const v4f*)headw)[tid];
    __syncthreads();
    if (tid < 32) sred[tid] = sred[tid] + sred[tid + 32] + sred[tid + 64] + sred[tid + 96];
    __syncthreads();
    if (tid == 0) {
      v4f a = *(const v4f*)headb;
#pragma unroll
      for (int q = 0; q < 32; ++q) a += sred[q];
      ((v4f*)(ws + B1H_OFF))[0] = a;
    }
  }
}

// ---------------- actor compute for one sample (obs row in sObs[tid*37..]) ----------------
__device__ __forceinline__ void actor_compute(
    const float* sObs, int tid, int gid,
    const float* __restrict__ ws,
    float ca0, float co0, float ca1, float co1,
    float* __restrict__ out)
{
  const v4f* __restrict__ tbl = (const v4f*)ws;

  float o[37];
#pragma unroll
  for (int i = 0; i < 37; i++) o[i] = sObs[tid * 37 + i];

  float qf[19];
#pragma unroll
  for (int i = 0; i < 12; i++) qf[i] = o[i];
#pragma unroll
  for (int i = 0; i < 7; i++) qf[12 + i] = o[30 + i];
  float nb[2][6];
#pragma unroll
  for (int k2 = 0; k2 < 2; k2++)
#pragma unroll
    for (int i = 0; i < 6; i++) nb[k2][i] = o[12 + 6 * k2 + i];
  const float nbv6[2] = { o[24], o[25] };
  const float obf[2][2] = { { o[26], o[27] }, { o[28], o[29] } };
  const float ax = o[0], ay = o[1];

  float dista[2], disto[2];
#pragma unroll
  for (int k2 = 0; k2 < 2; k2++) {
    float dx = ax - nb[k2][0], dy = ay - nb[k2][1];
    dista[k2] = sqrtf(dx * dx + dy * dy);
    float ex = ax - obf[k2][0], ey = ay - obf[k2][1];
    disto[k2] = sqrtf(ex * ex + ey * ey);
  }
  float dwa0[2], dwo0[2], dwa1[2], dwo1[2];
#pragma unroll
  for (int k2 = 0; k2 < 2; k2++) {
    dwa0[k2] = __expf(-ca0 * dista[k2]);
    dwo0[k2] = __expf(-co0 * disto[k2]);
    dwa1[k2] = __expf(-ca1 * dista[k2]);
    dwo1[k2] = __expf(-co1 * disto[k2]);
  }

  // layer 0 query fold (pre-scaled tables)
  v4f t0v[8];
#pragma unroll
  for (int z = 0; z < 8; z++) t0v[z] = (v4f)0.f;
#pragma unroll
  for (int h = 0; h < 4; h++) {
#pragma unroll
    for (int r = 0; r < 19; r++) {
      float q = qf[r];
      t0v[h * 2 + 0] += tbl[(h * 19 + r) * 2 + 0] * q;
      t0v[h * 2 + 1] += tbl[(h * 19 + r) * 2 + 1] * q;
    }
  }

  float wff[36];
#pragma unroll
  for (int h = 0; h < 4; h++) {
    float la[2], lo[2];
#pragma unroll
    for (int k2 = 0; k2 < 2; k2++) {
      float da = t0v[h*2][0]*nb[k2][0] + t0v[h*2][1]*nb[k2][1] + t0v[h*2][2]*nb[k2][2]
               + t0v[h*2][3]*nb[k2][3] + t0v[h*2+1][0]*nb[k2][4] + t0v[h*2+1][1]*nb[k2][5];
      la[k2] = da * dwa0[k2];
      float dof = t0v[h*2+1][2]*obf[k2][0] + t0v[h*2+1][3]*obf[k2][1];
      lo[k2] = dof * dwo0[k2];
    }
    float e  = __expf(la[1] - la[0]); float aa1 = e  / (1.f + e);  float aa0 = 1.f - aa1;
    float eo = __expf(lo[1] - lo[0]); float bo1 = eo / (1.f + eo); float bo0 = 1.f - bo1;
#pragma unroll
    for (int i = 0; i < 6; i++) wff[h * 9 + i] = aa0 * nb[0][i] + aa1 * nb[1][i];
    wff[h * 9 + 6] = aa0 * nbv6[0] + aa1 * nbv6[1];
    wff[h * 9 + 7] = bo0 * obf[0][0] + bo1 * obf[1][0];
    wff[h * 9 + 8] = bo0 * obf[0][1] + bo1 * obf[1][1];
  }

  // layer 1 query fold via M
  v4f t1v[8];
#pragma unroll
  for (int q = 0; q < 8; q++) t1v[q] = tbl[440 + q];
#pragma unroll
  for (int t = 0; t < 36; t++) {
    float f = wff[t];
#pragma unroll
    for (int q = 0; q < 8; q++)
      t1v[q] += tbl[152 + t * 8 + q] * f;
  }

  float wf1f[36];
#pragma unroll
  for (int h = 0; h < 4; h++) {
    float la[2], lo[2];
#pragma unroll
    for (int k2 = 0; k2 < 2; k2++) {
      float da = t1v[h*2][0]*nb[k2][0] + t1v[h*2][1]*nb[k2][1] + t1v[h*2][2]*nb[k2][2]
               + t1v[h*2][3]*nb[k2][3] + t1v[h*2+1][0]*nb[k2][4] + t1v[h*2+1][1]*nb[k2][5];
      la[k2] = da * dwa1[k2];
      float dof = t1v[h*2+1][2]*obf[k2][0] + t1v[h*2+1][3]*obf[k2][1];
      lo[k2] = dof * dwo1[k2];
    }
    float e  = __expf(la[1] - la[0]); float aa1 = e  / (1.f + e);  float aa0 = 1.f - aa1;
    float eo = __expf(lo[1] - lo[0]); float bo1 = eo / (1.f + eo); float bo0 = 1.f - bo1;
#pragma unroll
    for (int i = 0; i < 6; i++) wf1f[h * 9 + i] = aa0 * nb[0][i] + aa1 * nb[1][i];
    wf1f[h * 9 + 6] = aa0 * nbv6[0] + aa1 * nbv6[1];
    wf1f[h * 9 + 7] = bo0 * obf[0][0] + bo1 * obf[1][0];
    wf1f[h * 9 + 8] = bo0 * obf[0][1] + bo1 * obf[1][1];
  }

  v4f acc = tbl[484];
#pragma unroll
  for (int t = 0; t < 36; t++)
    acc += tbl[448 + t] * wf1f[t];
  ((v4f*)out)[gid] = acc;
}

// ---------------- kernel 1: one-shot self-contained prep ----------------
__global__ __launch_bounds__(NTH) void prep_one(
    const float* __restrict__ wq0,  const float* __restrict__ wak0, const float* __restrict__ wok0,
    const float* __restrict__ wav0, const float* __restrict__ wov0,
    const float* __restrict__ apw0, const float* __restrict__ opw0,
    const float* __restrict__ fpw0, const float* __restrict__ fpb0,
    const float* __restrict__ apb0, const float* __restrict__ opb0,
    const float* __restrict__ wq1,  const float* __restrict__ wak1, const float* __restrict__ wok1,
    const float* __restrict__ wav1, const float* __restrict__ wov1,
    const float* __restrict__ apw1, const float* __restrict__ opw1,
    const float* __restrict__ fpw1, const float* __restrict__ fpb1,
    const float* __restrict__ apb1, const float* __restrict__ opb1,
    const float* __restrict__ headw, const float* __restrict__ headb,
    float* __restrict__ ws)
{
  __shared__ v4f sred[NTH];
  __shared__ float sVecA[128];
  __shared__ float sVecB[512];
  __shared__ float sVecC[128];
  prep_block(blockIdx.x, threadIdx.x, wq0, wak0, wok0, wav0, wov0, apw0, opw0,
             fpw0, fpb0, apb0, opb0, wq1, wak1, wok1, wav1, wov1, apw1, opw1,
             fpw1, fpb1, apb1, opb1, headw, headb, ws, sred, sVecA, sVecB, sVecC);
}

// ---------------- kernel 2: actor (LDS-staged obs) ----------------
__global__ __launch_bounds__(NTH) void actor_k(
    const float* __restrict__ obs, const float* __restrict__ ws,
    const float* __restrict__ pca0, const float* __restrict__ pco0,
    const float* __restrict__ pca1, const float* __restrict__ pco1,
    float* __restrict__ out, int n)
{
  const int tid = threadIdx.x;
  const int gid = blockIdx.x * NTH + tid;
  __shared__ v4f sObsV[NTH * 37 / 4];
  float* sObs = (float*)sObsV;
  stage_obs(obs, sObsV, sObs, blockIdx.x, n, tid);
  __syncthreads();
  if (gid >= n) return;
  actor_compute(sObs, tid, gid, ws, pca0[0], pco0[0], pca1[0], pco1[0], out);
}

extern "C" void kernel_launch(void* const* d_in, const int* in_sizes, int n_in,
                              void* d_out, int out_size, void* d_ws, size_t ws_size,
                              hipStream_t stream)
{
  const float* obs  = (const float*)d_in[0];
  const float* wq0  = (const float*)d_in[1];
  const float* wak0 = (const float*)d_in[2];
  const float* wav0 = (const float*)d_in[3];
  const float* wok0 = (const float*)d_in[4];
  const float* wov0 = (const float*)d_in[5];
  const float* apw0 = (const float*)d_in[6];
  const float* apb0 = (const float*)d_in[7];
  const float* opw0 = (const float*)d_in[8];
  const float* opb0 = (const float*)d_in[9];
  const float* fpw0 = (const float*)d_in[10];
  const float* fpb0 = (const float*)d_in[11];
  const float* ca0  = (const float*)d_in[12];
  const float* co0  = (const float*)d_in[13];
  const float* wq1  = (const float*)d_in[14];
  const float* wak1 = (const float*)d_in[15];
  const float* wav1 = (const float*)d_in[16];
  const float* wok1 = (const float*)d_in[17];
  const float* wov1 = (const float*)d_in[18];
  const float* apw1 = (const float*)d_in[19];
  const float* apb1 = (const float*)d_in[20];
  const float* opw1 = (const float*)d_in[21];
  const float* opb1 = (const float*)d_in[22];
  const float* fpw1 = (const float*)d_in[23];
  const float* fpb1 = (const float*)d_in[24];
  const float* ca1  = (const float*)d_in[25];
  const float* co1  = (const float*)d_in[26];
  const float* headw = (const float*)d_in[27];
  const float* headb = (const float*)d_in[28];
  float* ws = (float*)d_ws;
  float* outp = (float*)d_out;
  int n = in_sizes[0] / 37;

  const int nblk = (n + NTH - 1) / NTH;

  prep_one<<<77, NTH, 0, stream>>>(
      wq0, wak0, wok0, wav0, wov0, apw0, opw0, fpw0, fpb0, apb0, opb0,
      wq1, wak1, wok1, wav1, wov1, apw1, opw1, fpw1, fpb1, apb1, opb1,
      headw, headb, ws);
  actor_k<<<nblk, NTH, 0, stream>>>(obs, ws, ca0, co0, ca1, co1, outp, n);
}